// Round 7
// baseline (349.223 us; speedup 1.0000x reference)
//
#include <hip/hip_runtime.h>
#include <hip/hip_bf16.h>

// Problem: B=64, S=1024, H=1024, A=512, E=512
// scores = tanh(encoded@W_enc + b_enc + states@W_dec + b_dec) . w_out (+b_out: softmax-invariant)
// weights = softmax(scores); attention = weights . encoded
// GRU: x=[inputs,attention]; gi=x@W_ih+b_ih; gh=states@W_hh+b_hh; gates -> h_new

typedef __attribute__((ext_vector_type(8))) __bf16 bf16x8;
typedef __attribute__((ext_vector_type(4))) __bf16 bf16x4;
typedef __attribute__((ext_vector_type(4))) float f32x4;

__device__ __forceinline__ float fast_tanh(float x) {
  float xa = fminf(fmaxf(x, -15.f), 15.f);
  float e = __expf(2.f * xa);
  return (e - 1.f) / (e + 1.f);
}

// global -> LDS direct DMA, 16B per lane. LDS dest = wave-uniform base + lane*16.
#define GLOAD16(G, L)                                                              \
  __builtin_amdgcn_global_load_lds(                                                \
      (const __attribute__((address_space(1))) unsigned int*)(const void*)(G),     \
      (__attribute__((address_space(3))) unsigned int*)(void*)(L), 16, 0, 0)

// ---------------- Kernel P: convert encoded f32 -> bf16 (streaming)
__global__ __launch_bounds__(256) void conv_kernel(const float* __restrict__ in,
                                                   __bf16* __restrict__ out, long n16) {
  long stride = (long)gridDim.x * 256;
  for (long i = (long)blockIdx.x * 256 + threadIdx.x; i < n16; i += stride) {
    const f32x4* p = (const f32x4*)(in + i * 16);
    f32x4 v0 = p[0], v1 = p[1], v2 = p[2], v3 = p[3];
    bf16x8 o0, o1;
#pragma unroll
    for (int j = 0; j < 4; ++j) {
      o0[j] = (__bf16)v0[j]; o0[4 + j] = (__bf16)v1[j];
      o1[j] = (__bf16)v2[j]; o1[4 + j] = (__bf16)v3[j];
    }
    *(bf16x8*)(out + i * 16) = o0;
    *(bf16x8*)(out + i * 16 + 8) = o1;
  }
}

// ---------------- Kernel T: transpose+convert W_enc [1024][512] f32 -> Wt [512][1024] bf16
__global__ __launch_bounds__(256) void wenc_t_kernel(const float* __restrict__ W,
                                                     __bf16* __restrict__ Wt) {
  __shared__ float tile[32][33];
  int k0 = blockIdx.x * 32, a0 = blockIdx.y * 32;
  int tid = threadIdx.x;
  int r = tid >> 3, c4 = (tid & 7) * 4;
  f32x4 v = *(const f32x4*)(W + (long)(k0 + r) * 512 + a0 + c4);
  tile[r][c4 + 0] = v.x; tile[r][c4 + 1] = v.y;
  tile[r][c4 + 2] = v.z; tile[r][c4 + 3] = v.w;
  __syncthreads();
  int a = tid >> 3, k4 = (tid & 7) * 4;
  bf16x4 o = { (__bf16)tile[k4 + 0][a], (__bf16)tile[k4 + 1][a],
               (__bf16)tile[k4 + 2][a], (__bf16)tile[k4 + 3][a] };
  *(bf16x4*)(Wt + (long)(a0 + a) * 1024 + k0 + k4) = o;
}

// ---------------- Kernel A: addv[b][a] = b_enc[a]+b_dec[a]+sum_h states[b,h]*W_dec[h,a]
__global__ __launch_bounds__(256) void dec_proj_kernel(
    const float* __restrict__ states, const float* __restrict__ W_dec,
    const float* __restrict__ b_enc, const float* __restrict__ b_dec,
    float* __restrict__ addv) {
  int b = blockIdx.x, tid = threadIdx.x;
  int a = blockIdx.y * 256 + tid;
  __shared__ float sl[1024];
  for (int i = tid; i < 1024; i += 256) sl[i] = states[b * 1024 + i];
  __syncthreads();
  float c0 = 0.f, c1 = 0.f, c2 = 0.f, c3 = 0.f;
#pragma unroll 4
  for (int i = 0; i < 256; ++i) {
    c0 += sl[i]         * W_dec[(i)        * 512 + a];
    c1 += sl[i + 256]   * W_dec[(i + 256)  * 512 + a];
    c2 += sl[i + 512]   * W_dec[(i + 512)  * 512 + a];
    c3 += sl[i + 768]   * W_dec[(i + 768)  * 512 + a];
  }
  addv[b * 512 + a] = c0 + c1 + c2 + c3 + b_enc[a] + b_dec[a];
}

// ---------------- Kernel B (primary): pure-bf16 m97 structure. 128x128, BK=32, 256 thr / 4 waves.
// LDS: A0@0 A1@8192 B0@16384 B1@24576 (each 128x64B), red@32768. 33792 B total.
// Swizzle: LDS granule (row,q) holds global k-chunk q^((row>>1)&3).
// Fragment read bank-group = 4*(lr&1) + (lkb^((lr>>1)&3)): all 8 groups x2 per quarter = free.
__global__ __launch_bounds__(256, 3) void enc_score_kernel(
    const __bf16* __restrict__ encB,  // [65536][1024] bf16
    const __bf16* __restrict__ Wt,    // [512][1024] bf16 (W_enc^T)
    const float* __restrict__ addv,   // [64][512]
    const float* __restrict__ w_out,  // [512]
    float* __restrict__ psc)          // [4][65536]
{
  __shared__ __attribute__((aligned(16))) char smem[33792];
  float* red = (float*)(smem + 32768);  // [128][2]

  const int d = blockIdx.x;
  const int xcd = d & 7;
  const int slot = d >> 3;
  const int bn = slot & 3;
  const int bm = ((slot >> 2) << 3) | xcd;  // bn-siblings share bm AND xcd

  const int tid = threadIdx.x;
  const int lane = tid & 63;
  const int wid = tid >> 6;   // 0..3
  const int wr = wid >> 1;    // 0..1
  const int wc = wid & 1;     // 0..1
  const int lr = lane & 15;
  const int lkb = lane >> 4;  // 0..3

  const long row0 = (long)bm * 128;
  const int col0 = bn * 128;

  // staging: granule g = round*256 + tid; row = g>>2 (row 0..63 / 64..127), slot' = g&3
  // source k-chunk = slot' ^ ((row>>1)&3)   (same for both rounds since +64 keeps (row>>1)&3)
  const int srow = tid >> 2;
  const int sk8 = (tid & 3) ^ ((srow >> 1) & 3);
  const __bf16* gA = encB + (row0 + srow) * 1024 + sk8 * 8;          // + kt*32 ; +64*1024 rnd1
  const __bf16* gB = Wt + (long)(col0 + srow) * 1024 + sk8 * 8;
  const int ldsW = wid * 1024;  // + round*4096

  // fragment read offsets
  const int foff = (lkb ^ ((lr >> 1) & 3)) << 4;
  const int aRowB = (wr * 64 + lr) * 64;  // + m*1024
  const int bColB = (wc * 64 + lr) * 64;  // + n*1024

  f32x4 acc[4][4];
#pragma unroll
  for (int m = 0; m < 4; ++m)
#pragma unroll
    for (int n = 0; n < 4; ++n) acc[m][n] = (f32x4){0.f, 0.f, 0.f, 0.f};

#define STAGE(BUF, KT) do {                                                        \
    GLOAD16(gA + (KT) * 32,           smem + (BUF) * 8192 + ldsW);                 \
    GLOAD16(gA + (KT) * 32 + 65536,   smem + (BUF) * 8192 + 4096 + ldsW);          \
    GLOAD16(gB + (KT) * 32,           smem + 16384 + (BUF) * 8192 + ldsW);         \
    GLOAD16(gB + (KT) * 32 + 65536,   smem + 16384 + (BUF) * 8192 + 4096 + ldsW);  \
  } while (0)

#define COMPUTE(BUF) do {                                                          \
    const char* _Ab = smem + (BUF) * 8192;                                         \
    const char* _Bb = smem + 16384 + (BUF) * 8192;                                 \
    bf16x8 _af[4], _bv[4];                                                         \
    _Pragma("unroll") for (int _m = 0; _m < 4; ++_m)                               \
      _af[_m] = *(const bf16x8*)(_Ab + aRowB + _m * 1024 + foff);                  \
    _Pragma("unroll") for (int _n = 0; _n < 4; ++_n)                               \
      _bv[_n] = *(const bf16x8*)(_Bb + bColB + _n * 1024 + foff);                  \
    _Pragma("unroll") for (int _m = 0; _m < 4; ++_m)                               \
      _Pragma("unroll") for (int _n = 0; _n < 4; ++_n)                             \
        acc[_m][_n] =                                                              \
            __builtin_amdgcn_mfma_f32_16x16x32_bf16(_af[_m], _bv[_n], acc[_m][_n], 0, 0, 0); \
  } while (0)

  STAGE(0, 0);
  __syncthreads();
  int buf = 0;
  for (int kt = 0; kt < 32; ++kt) {
    if (kt < 31) STAGE(buf ^ 1, kt + 1);
    COMPUTE(buf);
    __syncthreads();
    buf ^= 1;
  }

#undef STAGE
#undef COMPUTE

  // Epilogue: per-row sum of tanh(acc + addv[b][col]) * w_out[col]
  // C/D layout: col = lane&15, row = (lane>>4)*4 + reg
  const int b = bm >> 3;
  const float* addvb = addv + b * 512;
  float rowsum[4][4];
#pragma unroll
  for (int m = 0; m < 4; ++m)
#pragma unroll
    for (int reg = 0; reg < 4; ++reg) rowsum[m][reg] = 0.f;

#pragma unroll
  for (int m = 0; m < 4; ++m) {
#pragma unroll
    for (int n = 0; n < 4; ++n) {
      int col = col0 + wc * 64 + n * 16 + lr;
      float av = addvb[col];
      float wo = w_out[col];
#pragma unroll
      for (int reg = 0; reg < 4; ++reg)
        rowsum[m][reg] += fast_tanh(acc[m][n][reg] + av) * wo;
    }
  }
#pragma unroll
  for (int m = 0; m < 4; ++m)
#pragma unroll
    for (int reg = 0; reg < 4; ++reg) {
      float v = rowsum[m][reg];
      v += __shfl_xor(v, 1, 64);
      v += __shfl_xor(v, 2, 64);
      v += __shfl_xor(v, 4, 64);
      v += __shfl_xor(v, 8, 64);
      rowsum[m][reg] = v;
    }
  if (lr == 0) {
#pragma unroll
    for (int m = 0; m < 4; ++m)
#pragma unroll
      for (int reg = 0; reg < 4; ++reg)
        red[(wr * 64 + m * 16 + lkb * 4 + reg) * 2 + wc] = rowsum[m][reg];
  }
  __syncthreads();
  if (tid < 128)
    psc[(long)bn * 65536 + row0 + tid] = red[tid * 2] + red[tid * 2 + 1];
}

// ---------------- Kernel B (fallback, fp32 A, round-6 verbatim)
__global__ __launch_bounds__(256, 3) void enc_score_f32_kernel(
    const float* __restrict__ encoded, const __bf16* __restrict__ Wt,
    const float* __restrict__ addv, const float* __restrict__ w_out,
    float* __restrict__ psc) {
  __shared__ __attribute__((aligned(16))) char smem[50176];
  float* red = (float*)(smem + 49152);
  const int d = blockIdx.x;
  const int xcd = d & 7;
  const int slot = d >> 3;
  const int bn = slot & 3;
  const int bm = ((slot >> 2) << 3) | xcd;
  const int tid = threadIdx.x;
  const int lane = tid & 63;
  const int wid = tid >> 6;
  const int wr = wid >> 1, wc = wid & 1;
  const int lr = lane & 15, lkb = lane >> 4;
  const long row0 = (long)bm * 128;
  const int col0 = bn * 128;
  const int aslot = (tid & 7) ^ ((tid >> 3) & 7);
  const char* gA = (const char*)encoded + (row0 + (tid >> 3)) * 4096 + (aslot << 4);
  const int bslot = (tid & 3) ^ ((tid >> 3) & 3);
  const char* gB = (const char*)Wt + (long)(col0 + (tid >> 2)) * 2048 + (bslot << 4);
  const int ldsW = wid * 1024;
  const int aoff0 = ((2 * lkb) ^ (lr & 7)) << 4;
  const int aoff1 = ((2 * lkb + 1) ^ (lr & 7)) << 4;
  const int boff = (lkb ^ ((lr >> 1) & 3)) << 4;
  const int aRowB = (wr * 64 + lr) * 128;
  const int bColB = (wc * 64 + lr) * 64;
  f32x4 acc[4][4];
#pragma unroll
  for (int m = 0; m < 4; ++m)
#pragma unroll
    for (int n = 0; n < 4; ++n) acc[m][n] = (f32x4){0.f, 0.f, 0.f, 0.f};
#define STAGE(BUF, KT) do {                                                        \
    _Pragma("unroll") for (int _i = 0; _i < 4; ++_i)                               \
      GLOAD16(gA + (long)_i * 131072 + (KT) * 128,                                 \
              smem + (BUF) * 16384 + _i * 4096 + ldsW);                            \
    _Pragma("unroll") for (int _i = 0; _i < 2; ++_i)                               \
      GLOAD16(gB + (long)_i * 131072 + (KT) * 64,                                  \
              smem + 32768 + (BUF) * 8192 + _i * 4096 + ldsW);                     \
  } while (0)
#define COMPUTE(BUF) do {                                                          \
    const char* _Ab = smem + (BUF) * 16384;                                        \
    const char* _Bb = smem + 32768 + (BUF) * 8192;                                 \
    bf16x8 _af[4], _bv[4];                                                         \
    _Pragma("unroll") for (int _m = 0; _m < 4; ++_m) {                             \
      f32x4 _lo = *(const f32x4*)(_Ab + aRowB + _m * 2048 + aoff0);                \
      f32x4 _hi = *(const f32x4*)(_Ab + aRowB + _m * 2048 + aoff1);                \
      _Pragma("unroll") for (int _j = 0; _j < 4; ++_j) {                           \
        _af[_m][_j] = (__bf16)_lo[_j]; _af[_m][4 + _j] = (__bf16)_hi[_j];          \
      }                                                                            \
    }                                                                              \
    _Pragma("unroll") for (int _n = 0; _n < 4; ++_n)                               \
      _bv[_n] = *(const bf16x8*)(_Bb + bColB + _n * 1024 + boff);                  \
    _Pragma("unroll") for (int _m = 0; _m < 4; ++_m)                               \
      _Pragma("unroll") for (int _n = 0; _n < 4; ++_n)                             \
        acc[_m][_n] =                                                              \
            __builtin_amdgcn_mfma_f32_16x16x32_bf16(_af[_m], _bv[_n], acc[_m][_n], 0, 0, 0); \
  } while (0)
  STAGE(0, 0);
  __syncthreads();
  int buf = 0;
  for (int kt = 0; kt < 32; ++kt) {
    if (kt < 31) STAGE(buf ^ 1, kt + 1);
    COMPUTE(buf);
    __syncthreads();
    buf ^= 1;
  }
#undef STAGE
#undef COMPUTE
  const int b = bm >> 3;
  const float* addvb = addv + b * 512;
  float rowsum[4][4];
#pragma unroll
  for (int m = 0; m < 4; ++m)
#pragma unroll
    for (int reg = 0; reg < 4; ++reg) rowsum[m][reg] = 0.f;
#pragma unroll
  for (int m = 0; m < 4; ++m) {
#pragma unroll
    for (int n = 0; n < 4; ++n) {
      int col = col0 + wc * 64 + n * 16 + lr;
      float av = addvb[col];
      float wo = w_out[col];
#pragma unroll
      for (int reg = 0; reg < 4; ++reg)
        rowsum[m][reg] += fast_tanh(acc[m][n][reg] + av) * wo;
    }
  }
#pragma unroll
  for (int m = 0; m < 4; ++m)
#pragma unroll
    for (int reg = 0; reg < 4; ++reg) {
      float v = rowsum[m][reg];
      v += __shfl_xor(v, 1, 64);
      v += __shfl_xor(v, 2, 64);
      v += __shfl_xor(v, 4, 64);
      v += __shfl_xor(v, 8, 64);
      rowsum[m][reg] = v;
    }
  if (lr == 0) {
#pragma unroll
    for (int m = 0; m < 4; ++m)
#pragma unroll
      for (int reg = 0; reg < 4; ++reg)
        red[(wr * 64 + m * 16 + lkb * 4 + reg) * 2 + wc] = rowsum[m][reg];
  }
  __syncthreads();
  if (tid < 128)
    psc[(long)bn * 65536 + row0 + tid] = red[tid * 2] + red[tid * 2 + 1];
}

// ---------------- Kernel C: softmax over S=1024 per batch
__global__ __launch_bounds__(256) void softmax_kernel(const float* __restrict__ psc,
                                                      float* __restrict__ wts) {
  int b = blockIdx.x, tid = threadIdx.x;
  __shared__ float sred[8];
  float sc[4];
  float mx = -1e30f;
#pragma unroll
  for (int i = 0; i < 4; ++i) {
    long r = (long)b * 1024 + tid + i * 256;
    sc[i] = psc[r] + psc[65536 + r] + psc[2 * 65536 + r] + psc[3 * 65536 + r];
    mx = fmaxf(mx, sc[i]);
  }
  for (int off = 1; off < 64; off <<= 1) mx = fmaxf(mx, __shfl_xor(mx, off, 64));
  if ((tid & 63) == 0) sred[tid >> 6] = mx;
  __syncthreads();
  mx = fmaxf(fmaxf(sred[0], sred[1]), fmaxf(sred[2], sred[3]));
  float e[4], sum = 0.f;
#pragma unroll
  for (int i = 0; i < 4; ++i) {
    e[i] = __expf(sc[i] - mx);
    sum += e[i];
  }
  for (int off = 1; off < 64; off <<= 1) sum += __shfl_xor(sum, off, 64);
  if ((tid & 63) == 0) sred[4 + (tid >> 6)] = sum;
  __syncthreads();
  sum = sred[4] + sred[5] + sred[6] + sred[7];
  float inv = 1.f / sum;
#pragma unroll
  for (int i = 0; i < 4; ++i) wts[(long)b * 1024 + tid + i * 256] = e[i] * inv;
}

// ---------------- Kernel D (primary): attention partials from bf16 encB
__global__ __launch_bounds__(128) void att_part_bf16_kernel(const __bf16* __restrict__ encB,
                                                            const float* __restrict__ wts,
                                                            float* __restrict__ attp) {
  int chunk = blockIdx.x;  // 16
  int b = blockIdx.y;      // 64
  int tid = threadIdx.x;   // 0..127 -> h octet
  const __bf16* base = encB + ((long)b * 1024 + chunk * 64) * 1024 + tid * 8;
  const float* w = wts + b * 1024 + chunk * 64;
  float a0[8], a1[8];
#pragma unroll
  for (int j = 0; j < 8; ++j) { a0[j] = 0.f; a1[j] = 0.f; }
#pragma unroll 4
  for (int s = 0; s < 64; s += 2) {
    bf16x8 v0 = *(const bf16x8*)(base + (long)s * 1024);
    bf16x8 v1 = *(const bf16x8*)(base + (long)(s + 1) * 1024);
    float w0 = w[s], w1 = w[s + 1];
#pragma unroll
    for (int j = 0; j < 8; ++j) {
      a0[j] += (float)v0[j] * w0;
      a1[j] += (float)v1[j] * w1;
    }
  }
  float* o = attp + ((long)(b * 16 + chunk)) * 1024 + tid * 8;
#pragma unroll
  for (int j = 0; j < 8; ++j) o[j] = a0[j] + a1[j];
}

// ---------------- Kernel D (fallback): fp32 encoded
__global__ __launch_bounds__(256) void att_part_kernel(const float* __restrict__ encoded,
                                                       const float* __restrict__ wts,
                                                       float* __restrict__ attp) {
  int chunk = blockIdx.x;
  int b = blockIdx.y;
  int tid = threadIdx.x;
  f32x4 a0 = (f32x4){0.f, 0.f, 0.f, 0.f};
  f32x4 a1 = a0, a2 = a0, a3 = a0;
  const float* base = encoded + ((long)b * 1024 + chunk * 64) * 1024 + tid * 4;
  const float* w = wts + b * 1024 + chunk * 64;
#pragma unroll 4
  for (int s = 0; s < 64; s += 4) {
    f32x4 v0 = *(const f32x4*)(base + (long)(s + 0) * 1024);
    f32x4 v1 = *(const f32x4*)(base + (long)(s + 1) * 1024);
    f32x4 v2 = *(const f32x4*)(base + (long)(s + 2) * 1024);
    f32x4 v3 = *(const f32x4*)(base + (long)(s + 3) * 1024);
    a0 += v0 * w[s]; a1 += v1 * w[s + 1]; a2 += v2 * w[s + 2]; a3 += v3 * w[s + 3];
  }
  *(f32x4*)(attp + ((long)(b * 16 + chunk)) * 1024 + tid * 4) = (a0 + a1) + (a2 + a3);
}

// ---------------- Kernel E: xcat[b][0:512]=inputs, xcat[b][512:1536]=sum_chunk attp
__global__ __launch_bounds__(256) void xcat_kernel(const float* __restrict__ inputs,
                                                   const float* __restrict__ attp,
                                                   float* __restrict__ xcat) {
  int b = blockIdx.y;
  int k = blockIdx.x * 256 + threadIdx.x;  // 0..1535
  float v;
  if (k < 512) {
    v = inputs[b * 512 + k];
  } else {
    int h = k - 512;
    v = 0.f;
#pragma unroll
    for (int c = 0; c < 16; ++c) v += attp[((long)(b * 16 + c)) * 1024 + h];
  }
  xcat[(long)b * 1536 + k] = v;
}

// ---------------- Kernel F: GRU GEMVs, batch-grouped: chunk-group pinned to one XCD
__global__ __launch_bounds__(512) void gru_gemv_kernel(
    const float* __restrict__ xcat, const float* __restrict__ states,
    const float* __restrict__ W_ih, const float* __restrict__ b_ih,
    const float* __restrict__ W_hh, const float* __restrict__ b_hh,
    float* __restrict__ gi, float* __restrict__ gh) {
  __shared__ float sx[12288];
  const int dd = blockIdx.x;            // 192
  const int xcd = dd & 7;
  const int n = dd >> 3;
  const int cgrp = xcd + 8 * (n >> 3);
  const int bg = n & 7;
  const int tid = threadIdx.x;
  const int lcol = tid & 255;
  const int bsel = (tid >> 8) * 4;

  if (cgrp < 12) {
    const int col = cgrp * 256 + lcol;
    const float* xb = xcat + (long)bg * 8 * 1536;
    for (int i = tid; i < 3072; i += 512) ((f32x4*)sx)[i] = ((const f32x4*)xb)[i];
    __syncthreads();
    float a0 = b_ih[col], a1 = a0, a2 = a0, a3 = a0;
    const float* x0 = sx + (bsel + 0) * 1536;
    const float* x1 = sx + (bsel + 1) * 1536;
    const float* x2 = sx + (bsel + 2) * 1536;
    const float* x3 = sx + (bsel + 3) * 1536;
    for (int k = 0; k < 1536; k += 4) {
      f32x4 v0 = *(const f32x4*)(x0 + k);
      f32x4 v1 = *(const f32x4*)(x1 + k);
      f32x4 v2 = *(const f32x4*)(x2 + k);
      f32x4 v3 = *(const f32x4*)(x3 + k);
#pragma unroll
      for (int j = 0; j < 4; ++j) {
        float w = W_ih[(long)(k + j) * 3072 + col];
        a0 += v0[j] * w; a1 += v1[j] * w; a2 += v2[j] * w; a3 += v3[j] * w;
      }
    }
    long o = (long)(bg * 8 + bsel) * 3072 + col;
    gi[o] = a0; gi[o + 3072] = a1; gi[o + 6144] = a2; gi[o + 9216] = a3;
  } else {
    const int col = (cgrp - 12) * 256 + lcol;
    const float* sb = states + (long)bg * 8 * 1024;
    for (int i = tid; i < 2048; i += 512) ((f32x4*)sx)[i] = ((const f32x4*)sb)[i];
    __syncthreads();
    float a0 = b_hh[col], a1 = a0, a2 = a0, a3 = a0;
    const float* x0 = sx + (bsel + 0) * 1024;
    const float* x1 = sx + (bsel + 1) * 1024;
    const float* x2 = sx + (bsel + 2) * 1024;
    const float* x3 = sx + (bsel + 3) * 1024;
    for (int k = 0; k < 1024; k += 4) {
      f32x4 v0 = *(const f32x4*)(x0 + k);
      f32x4 v1 = *(const f32x4*)(x1 + k);
      f32x4 v2 = *(const f32x4*)(x2 + k);
      f32x4 v3 = *(const f32x4*)(x3 + k);
#pragma unroll
      for (int j = 0; j < 4; ++j) {
        float w = W_hh[(long)(k + j) * 3072 + col];
        a0 += v0[j] * w; a1 += v1[j] * w; a2 += v2[j] * w; a3 += v3[j] * w;
      }
    }
    long o = (long)(bg * 8 + bsel) * 3072 + col;
    gh[o] = a0; gh[o + 3072] = a1; gh[o + 6144] = a2; gh[o + 9216] = a3;
  }
}

// ---------------- Kernel G: gates
__global__ __launch_bounds__(256) void gate_kernel(const float* __restrict__ gi,
                                                   const float* __restrict__ gh,
                                                   const float* __restrict__ states,
                                                   float* __restrict__ out) {
  int b = blockIdx.y;
  int j = blockIdx.x * 256 + threadIdx.x;
  long o = (long)b * 3072;
  float ir = gi[o + j], hr = gh[o + j];
  float iz = gi[o + 1024 + j], hz = gh[o + 1024 + j];
  float in_ = gi[o + 2048 + j], hn = gh[o + 2048 + j];
  float r = 1.f / (1.f + __expf(-(ir + hr)));
  float z = 1.f / (1.f + __expf(-(iz + hz)));
  float n = fast_tanh(in_ + r * hn);
  out[(long)b * 1024 + j] = (1.f - z) * n + z * states[(long)b * 1024 + j];
}

extern "C" void kernel_launch(void* const* d_in, const int* in_sizes, int n_in,
                              void* d_out, int out_size, void* d_ws, size_t ws_size,
                              hipStream_t stream) {
  const float* inputs  = (const float*)d_in[0];
  const float* states  = (const float*)d_in[1];
  const float* encoded = (const float*)d_in[2];
  const float* W_enc   = (const float*)d_in[3];
  const float* b_enc   = (const float*)d_in[4];
  const float* W_dec   = (const float*)d_in[5];
  const float* b_dec   = (const float*)d_in[6];
  const float* w_out   = (const float*)d_in[7];
  // d_in[8] = b_out: softmax-invariant, unused
  const float* W_ih    = (const float*)d_in[9];
  const float* b_ih    = (const float*)d_in[10];
  const float* W_hh    = (const float*)d_in[11];
  const float* b_hh    = (const float*)d_in[12];
  float* out = (float*)d_out;
  float* ws = (float*)d_ws;

  const long ENC_ELEMS = 64L * 1024 * 1024;          // encoded element count
  const long ENCB_FLOATS = ENC_ELEMS / 2;            // 33554432 float slots for bf16 copy
  const long OTHERS_FLOATS = 2162688;
  const bool big = ws_size >= (size_t)(ENCB_FLOATS + OTHERS_FLOATS) * 4;

  __bf16* encB = (__bf16*)ws;                        // big path only
  float* base = big ? ws + ENCB_FLOATS : ws;

  float* addv = base;                 // 32768
  float* psc  = base + 32768;         // 262144
  float* wts  = base + 294912;        // 65536
  float* attp = base + 360448;        // 64*16*1024 = 1048576
  float* xcat = base + 1409024;       // 98304
  float* gi   = base + 1507328;       // 196608
  float* gh   = base + 1703936;       // 196608
  __bf16* Wt  = (__bf16*)(base + 1900544);  // 512*1024 bf16 (262144 float slots)

  if (big) conv_kernel<<<4096, 256, 0, stream>>>(encoded, encB, ENC_ELEMS / 16);

  wenc_t_kernel<<<dim3(32, 16), 256, 0, stream>>>(W_enc, Wt);

  dim3 gA(64, 2);
  dec_proj_kernel<<<gA, 256, 0, stream>>>(states, W_dec, b_enc, b_dec, addv);

  if (big)
    enc_score_kernel<<<2048, 256, 0, stream>>>(encB, Wt, addv, w_out, psc);
  else
    enc_score_f32_kernel<<<2048, 256, 0, stream>>>(encoded, Wt, addv, w_out, psc);

  softmax_kernel<<<64, 256, 0, stream>>>(psc, wts);

  dim3 gD(16, 64);
  if (big)
    att_part_bf16_kernel<<<gD, 128, 0, stream>>>(encB, wts, attp);
  else
    att_part_kernel<<<gD, 256, 0, stream>>>(encoded, wts, attp);

  dim3 gE(6, 64);
  xcat_kernel<<<gE, 256, 0, stream>>>(inputs, attp, xcat);

  gru_gemv_kernel<<<192, 512, 0, stream>>>(xcat, states, W_ih, b_ih, W_hh, b_hh, gi, gh);

  dim3 gG(4, 64);
  gate_kernel<<<gG, 256, 0, stream>>>(gi, gh, states, out);
}

// Round 8
// 341.437 us; speedup vs baseline: 1.0228x; 1.0228x over previous
//
#include <hip/hip_runtime.h>
#include <hip/hip_bf16.h>

// Problem: B=64, S=1024, H=1024, A=512, E=512
// scores = tanh(encoded@W_enc + b_enc + states@W_dec + b_dec) . w_out (+b_out: softmax-invariant)
// weights = softmax(scores); attention = weights . encoded
// GRU: x=[inputs,attention]; gi=x@W_ih+b_ih; gh=states@W_hh+b_hh; gates -> h_new

typedef __attribute__((ext_vector_type(8))) __bf16 bf16x8;
typedef __attribute__((ext_vector_type(4))) __bf16 bf16x4;
typedef __attribute__((ext_vector_type(4))) float f32x4;

__device__ __forceinline__ float fast_tanh(float x) {
  float xa = fminf(fmaxf(x, -15.f), 15.f);
  float e = __expf(2.f * xa);
  return (e - 1.f) / (e + 1.f);
}

// global -> LDS direct DMA, 16B per lane. LDS dest = wave-uniform base + lane*16.
#define GLOAD16(G, L)                                                              \
  __builtin_amdgcn_global_load_lds(                                                \
      (const __attribute__((address_space(1))) unsigned int*)(const void*)(G),     \
      (__attribute__((address_space(3))) unsigned int*)(void*)(L), 16, 0, 0)

// ---------------- Kernel P: convert encoded f32 -> bf16 (streaming)
__global__ __launch_bounds__(256) void conv_kernel(const float* __restrict__ in,
                                                   __bf16* __restrict__ out, long n16) {
  long stride = (long)gridDim.x * 256;
  for (long i = (long)blockIdx.x * 256 + threadIdx.x; i < n16; i += stride) {
    const f32x4* p = (const f32x4*)(in + i * 16);
    f32x4 v0 = p[0], v1 = p[1], v2 = p[2], v3 = p[3];
    bf16x8 o0, o1;
#pragma unroll
    for (int j = 0; j < 4; ++j) {
      o0[j] = (__bf16)v0[j]; o0[4 + j] = (__bf16)v1[j];
      o1[j] = (__bf16)v2[j]; o1[4 + j] = (__bf16)v3[j];
    }
    *(bf16x8*)(out + i * 16) = o0;
    *(bf16x8*)(out + i * 16 + 8) = o1;
  }
}

// ---------------- Kernel T: transpose+convert W_enc [1024][512] f32 -> Wt [512][1024] bf16
__global__ __launch_bounds__(256) void wenc_t_kernel(const float* __restrict__ W,
                                                     __bf16* __restrict__ Wt) {
  __shared__ float tile[32][33];
  int k0 = blockIdx.x * 32, a0 = blockIdx.y * 32;
  int tid = threadIdx.x;
  int r = tid >> 3, c4 = (tid & 7) * 4;
  f32x4 v = *(const f32x4*)(W + (long)(k0 + r) * 512 + a0 + c4);
  tile[r][c4 + 0] = v.x; tile[r][c4 + 1] = v.y;
  tile[r][c4 + 2] = v.z; tile[r][c4 + 3] = v.w;
  __syncthreads();
  int a = tid >> 3, k4 = (tid & 7) * 4;
  bf16x4 o = { (__bf16)tile[k4 + 0][a], (__bf16)tile[k4 + 1][a],
               (__bf16)tile[k4 + 2][a], (__bf16)tile[k4 + 3][a] };
  *(bf16x4*)(Wt + (long)(a0 + a) * 1024 + k0 + k4) = o;
}

// ---------------- Kernel A: addv[b][a] = b_enc[a]+b_dec[a]+sum_h states[b,h]*W_dec[h,a]
__global__ __launch_bounds__(256) void dec_proj_kernel(
    const float* __restrict__ states, const float* __restrict__ W_dec,
    const float* __restrict__ b_enc, const float* __restrict__ b_dec,
    float* __restrict__ addv) {
  int b = blockIdx.x, tid = threadIdx.x;
  int a = blockIdx.y * 256 + tid;
  __shared__ float sl[1024];
  for (int i = tid; i < 1024; i += 256) sl[i] = states[b * 1024 + i];
  __syncthreads();
  float c0 = 0.f, c1 = 0.f, c2 = 0.f, c3 = 0.f;
#pragma unroll 4
  for (int i = 0; i < 256; ++i) {
    c0 += sl[i]         * W_dec[(i)        * 512 + a];
    c1 += sl[i + 256]   * W_dec[(i + 256)  * 512 + a];
    c2 += sl[i + 512]   * W_dec[(i + 512)  * 512 + a];
    c3 += sl[i + 768]   * W_dec[(i + 768)  * 512 + a];
  }
  addv[b * 512 + a] = c0 + c1 + c2 + c3 + b_enc[a] + b_dec[a];
}

// ---------------- Kernel B: 256x256 tile, BK=32, 512 thr / 8 waves (2x4, wave = 128x64).
// Triple-buffered LDS + counted vmcnt(4) across raw s_barrier (T3/T4): 2 tiles always in
// flight, never drained to 0 in the loop. gload_lds staging with involution source swizzle
// q^((row>>1)&3) (verified R7). Staged bytes halved vs 128^2: 512 blocks x 1MB = 512MB.
// LDS: A bufs 3x16KB @0, B bufs 3x16KB @49152, red 4KB @98304.
__global__ __launch_bounds__(512, 2) void enc_score_kernel(
    const __bf16* __restrict__ encB,  // [65536][1024] bf16
    const __bf16* __restrict__ Wt,    // [512][1024] bf16 (W_enc^T)
    const float* __restrict__ addv,   // [64][512]
    const float* __restrict__ w_out,  // [512]
    float* __restrict__ psc)          // [2][65536]
{
  __shared__ __attribute__((aligned(16))) char smem[102400];
  float* red = (float*)(smem + 98304);  // [256][4]

  const int d = blockIdx.x;   // 512
  const int xcd = d & 7;
  const int slot = d >> 3;    // 0..63
  const int bn = slot & 1;
  const int bm = ((slot >> 1) << 3) | xcd;  // 0..255; bn-siblings share bm AND xcd

  const int tid = threadIdx.x;
  const int lane = tid & 63;
  const int wid = tid >> 6;   // 0..7
  const int wr = wid >> 2;    // 0..1 (128 rows)
  const int wc = wid & 3;     // 0..3 (64 cols)
  const int lr = lane & 15;
  const int lkb = lane >> 4;  // 0..3

  const long row0 = (long)bm * 256;
  const int col0 = bn * 256;

  // staging: granule (row, q), row = (tid>>2) + 128*round, q = tid&3 (16B chunks of 64B k-slab)
  // source chunk = q ^ ((row>>1)&3)  (involution; round +128 preserves bits 1-2)
  const int sk8 = (tid & 3) ^ ((tid >> 3) & 3);
  const __bf16* gA = encB + (row0 + (tid >> 2)) * 1024 + sk8 * 8;
  const __bf16* gB = Wt + (long)(col0 + (tid >> 2)) * 1024 + sk8 * 8;
  const int ldsW = wid * 1024;  // + round*8192; lane*16 added by HW

  // fragment read: global chunk lkb lives in LDS slot lkb ^ ((row>>1)&3), row bits1-2 == lr bits1-2
  const int foff = (lkb ^ ((lr >> 1) & 3)) << 4;
  const int aRowB = (wr * 128 + lr) * 64;  // + m*1024 (16 rows)
  const int bColB = (wc * 64 + lr) * 64;   // + n*1024

  f32x4 acc[8][4];
#pragma unroll
  for (int m = 0; m < 8; ++m)
#pragma unroll
    for (int n = 0; n < 4; ++n) acc[m][n] = (f32x4){0.f, 0.f, 0.f, 0.f};

#define STAGE(SBUF, KT) do {                                                       \
    const __bf16* _a = gA + (KT) * 32;                                             \
    const __bf16* _b = gB + (KT) * 32;                                             \
    GLOAD16(_a,          smem + (SBUF) * 16384 + ldsW);                            \
    GLOAD16(_a + 131072, smem + (SBUF) * 16384 + 8192 + ldsW);                     \
    GLOAD16(_b,          smem + 49152 + (SBUF) * 16384 + ldsW);                    \
    GLOAD16(_b + 131072, smem + 49152 + (SBUF) * 16384 + 8192 + ldsW);             \
    __builtin_amdgcn_sched_barrier(0);                                             \
  } while (0)

#define COMPUTE(CBUF) do {                                                         \
    const char* _Ab = smem + (CBUF) * 16384;                                       \
    const char* _Bb = smem + 49152 + (CBUF) * 16384;                               \
    bf16x8 _af[8], _bv[4];                                                         \
    _Pragma("unroll") for (int _m = 0; _m < 8; ++_m)                               \
      _af[_m] = *(const bf16x8*)(_Ab + aRowB + _m * 1024 + foff);                  \
    _Pragma("unroll") for (int _n = 0; _n < 4; ++_n)                               \
      _bv[_n] = *(const bf16x8*)(_Bb + bColB + _n * 1024 + foff);                  \
    __builtin_amdgcn_s_setprio(1);                                                 \
    _Pragma("unroll") for (int _m = 0; _m < 8; ++_m)                               \
      _Pragma("unroll") for (int _n = 0; _n < 4; ++_n)                             \
        acc[_m][_n] =                                                              \
            __builtin_amdgcn_mfma_f32_16x16x32_bf16(_af[_m], _bv[_n], acc[_m][_n], 0, 0, 0); \
    __builtin_amdgcn_s_setprio(0);                                                 \
  } while (0)

#define ITER(KT, CBUF, SBUF) do {                                                  \
    asm volatile("s_waitcnt vmcnt(4)" ::: "memory");                               \
    __builtin_amdgcn_sched_barrier(0);                                             \
    __builtin_amdgcn_s_barrier();                                                  \
    __builtin_amdgcn_sched_barrier(0);                                             \
    COMPUTE(CBUF);                                                                 \
    asm volatile("s_waitcnt lgkmcnt(0)" ::: "memory");                             \
    __builtin_amdgcn_sched_barrier(0);                                             \
    __builtin_amdgcn_s_barrier();                                                  \
    __builtin_amdgcn_sched_barrier(0);                                             \
    STAGE(SBUF, (KT) + 2);                                                         \
  } while (0)

  // prologue: tiles 0,1 in flight (8 outstanding loads/thread)
  STAGE(0, 0);
  STAGE(1, 1);

  for (int k3 = 0; k3 < 30; k3 += 3) {
    ITER(k3 + 0, 0, 2);
    ITER(k3 + 1, 1, 0);
    ITER(k3 + 2, 2, 1);
  }
  // kt=30: compute buf0 (t30); t31 stays in flight
  asm volatile("s_waitcnt vmcnt(4)" ::: "memory");
  __builtin_amdgcn_sched_barrier(0);
  __builtin_amdgcn_s_barrier();
  __builtin_amdgcn_sched_barrier(0);
  COMPUTE(0);
  // kt=31: full drain, compute buf1 (t31)
  asm volatile("s_waitcnt vmcnt(0)" ::: "memory");
  __builtin_amdgcn_sched_barrier(0);
  __builtin_amdgcn_s_barrier();
  __builtin_amdgcn_sched_barrier(0);
  COMPUTE(1);

#undef STAGE
#undef COMPUTE
#undef ITER

  // Epilogue: per-row sum of tanh(acc + addv[b][col]) * w_out[col]
  // C/D layout: col = lane&15, row = (lane>>4)*4 + reg
  const int b = bm >> 2;  // 256 rows/block, 1024/batch
  const float* addvb = addv + b * 512;
  float rowsum[8][4];
#pragma unroll
  for (int m = 0; m < 8; ++m)
#pragma unroll
    for (int reg = 0; reg < 4; ++reg) rowsum[m][reg] = 0.f;

#pragma unroll
  for (int m = 0; m < 8; ++m) {
#pragma unroll
    for (int n = 0; n < 4; ++n) {
      int col = col0 + wc * 64 + n * 16 + lr;
      float av = addvb[col];
      float wo = w_out[col];
#pragma unroll
      for (int reg = 0; reg < 4; ++reg)
        rowsum[m][reg] += fast_tanh(acc[m][n][reg] + av) * wo;
    }
  }
#pragma unroll
  for (int m = 0; m < 8; ++m)
#pragma unroll
    for (int reg = 0; reg < 4; ++reg) {
      float v = rowsum[m][reg];
      v += __shfl_xor(v, 1, 64);
      v += __shfl_xor(v, 2, 64);
      v += __shfl_xor(v, 4, 64);
      v += __shfl_xor(v, 8, 64);
      rowsum[m][reg] = v;
    }
  __syncthreads();  // all compute done; red region free
  if (lr == 0) {
#pragma unroll
    for (int m = 0; m < 8; ++m)
#pragma unroll
      for (int reg = 0; reg < 4; ++reg)
        red[(wr * 128 + m * 16 + lkb * 4 + reg) * 4 + wc] = rowsum[m][reg];
  }
  __syncthreads();
  if (tid < 256)
    psc[(long)bn * 65536 + row0 + tid] =
        red[tid * 4] + red[tid * 4 + 1] + red[tid * 4 + 2] + red[tid * 4 + 3];
}

// ---------------- Kernel C: softmax over S=1024 per batch (2 psc partials now)
__global__ __launch_bounds__(256) void softmax_kernel(const float* __restrict__ psc,
                                                      float* __restrict__ wts) {
  int b = blockIdx.x, tid = threadIdx.x;
  __shared__ float sred[8];
  float sc[4];
  float mx = -1e30f;
#pragma unroll
  for (int i = 0; i < 4; ++i) {
    long r = (long)b * 1024 + tid + i * 256;
    sc[i] = psc[r] + psc[65536 + r];
    mx = fmaxf(mx, sc[i]);
  }
  for (int off = 1; off < 64; off <<= 1) mx = fmaxf(mx, __shfl_xor(mx, off, 64));
  if ((tid & 63) == 0) sred[tid >> 6] = mx;
  __syncthreads();
  mx = fmaxf(fmaxf(sred[0], sred[1]), fmaxf(sred[2], sred[3]));
  float e[4], sum = 0.f;
#pragma unroll
  for (int i = 0; i < 4; ++i) {
    e[i] = __expf(sc[i] - mx);
    sum += e[i];
  }
  for (int off = 1; off < 64; off <<= 1) sum += __shfl_xor(sum, off, 64);
  if ((tid & 63) == 0) sred[4 + (tid >> 6)] = sum;
  __syncthreads();
  sum = sred[4] + sred[5] + sred[6] + sred[7];
  float inv = 1.f / sum;
#pragma unroll
  for (int i = 0; i < 4; ++i) wts[(long)b * 1024 + tid + i * 256] = e[i] * inv;
}

// ---------------- Kernel D: attention partials from bf16 encB (16 chunks of 64 s)
__global__ __launch_bounds__(128) void att_part_bf16_kernel(const __bf16* __restrict__ encB,
                                                            const float* __restrict__ wts,
                                                            float* __restrict__ attp) {
  int chunk = blockIdx.x;  // 16
  int b = blockIdx.y;      // 64
  int tid = threadIdx.x;   // 0..127 -> h octet
  const __bf16* base = encB + ((long)b * 1024 + chunk * 64) * 1024 + tid * 8;
  const float* w = wts + b * 1024 + chunk * 64;
  float a0[8], a1[8];
#pragma unroll
  for (int j = 0; j < 8; ++j) { a0[j] = 0.f; a1[j] = 0.f; }
#pragma unroll 4
  for (int s = 0; s < 64; s += 2) {
    bf16x8 v0 = *(const bf16x8*)(base + (long)s * 1024);
    bf16x8 v1 = *(const bf16x8*)(base + (long)(s + 1) * 1024);
    float w0 = w[s], w1 = w[s + 1];
#pragma unroll
    for (int j = 0; j < 8; ++j) {
      a0[j] += (float)v0[j] * w0;
      a1[j] += (float)v1[j] * w1;
    }
  }
  float* o = attp + ((long)(b * 16 + chunk)) * 1024 + tid * 8;
#pragma unroll
  for (int j = 0; j < 8; ++j) o[j] = a0[j] + a1[j];
}

// ---------------- Kernel E: xcat[b][0:512]=inputs, xcat[b][512:1536]=sum_chunk attp
__global__ __launch_bounds__(256) void xcat_kernel(const float* __restrict__ inputs,
                                                   const float* __restrict__ attp,
                                                   float* __restrict__ xcat) {
  int b = blockIdx.y;
  int k = blockIdx.x * 256 + threadIdx.x;  // 0..1535
  float v;
  if (k < 512) {
    v = inputs[b * 512 + k];
  } else {
    int h = k - 512;
    v = 0.f;
#pragma unroll
    for (int c = 0; c < 16; ++c) v += attp[((long)(b * 16 + c)) * 1024 + h];
  }
  xcat[(long)b * 1536 + k] = v;
}

// ---------------- Kernel F: GRU GEMVs, batch-grouped: chunk-group pinned to one XCD
__global__ __launch_bounds__(512) void gru_gemv_kernel(
    const float* __restrict__ xcat, const float* __restrict__ states,
    const float* __restrict__ W_ih, const float* __restrict__ b_ih,
    const float* __restrict__ W_hh, const float* __restrict__ b_hh,
    float* __restrict__ gi, float* __restrict__ gh) {
  __shared__ float sx[12288];
  const int dd = blockIdx.x;            // 192
  const int xcd = dd & 7;
  const int n = dd >> 3;
  const int cgrp = xcd + 8 * (n >> 3);
  const int bg = n & 7;
  const int tid = threadIdx.x;
  const int lcol = tid & 255;
  const int bsel = (tid >> 8) * 4;

  if (cgrp < 12) {
    const int col = cgrp * 256 + lcol;
    const float* xb = xcat + (long)bg * 8 * 1536;
    for (int i = tid; i < 3072; i += 512) ((f32x4*)sx)[i] = ((const f32x4*)xb)[i];
    __syncthreads();
    float a0 = b_ih[col], a1 = a0, a2 = a0, a3 = a0;
    const float* x0 = sx + (bsel + 0) * 1536;
    const float* x1 = sx + (bsel + 1) * 1536;
    const float* x2 = sx + (bsel + 2) * 1536;
    const float* x3 = sx + (bsel + 3) * 1536;
    for (int k = 0; k < 1536; k += 4) {
      f32x4 v0 = *(const f32x4*)(x0 + k);
      f32x4 v1 = *(const f32x4*)(x1 + k);
      f32x4 v2 = *(const f32x4*)(x2 + k);
      f32x4 v3 = *(const f32x4*)(x3 + k);
#pragma unroll
      for (int j = 0; j < 4; ++j) {
        float w = W_ih[(long)(k + j) * 3072 + col];
        a0 += v0[j] * w; a1 += v1[j] * w; a2 += v2[j] * w; a3 += v3[j] * w;
      }
    }
    long o = (long)(bg * 8 + bsel) * 3072 + col;
    gi[o] = a0; gi[o + 3072] = a1; gi[o + 6144] = a2; gi[o + 9216] = a3;
  } else {
    const int col = (cgrp - 12) * 256 + lcol;
    const float* sb = states + (long)bg * 8 * 1024;
    for (int i = tid; i < 2048; i += 512) ((f32x4*)sx)[i] = ((const f32x4*)sb)[i];
    __syncthreads();
    float a0 = b_hh[col], a1 = a0, a2 = a0, a3 = a0;
    const float* x0 = sx + (bsel + 0) * 1024;
    const float* x1 = sx + (bsel + 1) * 1024;
    const float* x2 = sx + (bsel + 2) * 1024;
    const float* x3 = sx + (bsel + 3) * 1024;
    for (int k = 0; k < 1024; k += 4) {
      f32x4 v0 = *(const f32x4*)(x0 + k);
      f32x4 v1 = *(const f32x4*)(x1 + k);
      f32x4 v2 = *(const f32x4*)(x2 + k);
      f32x4 v3 = *(const f32x4*)(x3 + k);
#pragma unroll
      for (int j = 0; j < 4; ++j) {
        float w = W_hh[(long)(k + j) * 3072 + col];
        a0 += v0[j] * w; a1 += v1[j] * w; a2 += v2[j] * w; a3 += v3[j] * w;
      }
    }
    long o = (long)(bg * 8 + bsel) * 3072 + col;
    gh[o] = a0; gh[o + 3072] = a1; gh[o + 6144] = a2; gh[o + 9216] = a3;
  }
}

// ---------------- Kernel G: gates
__global__ __launch_bounds__(256) void gate_kernel(const float* __restrict__ gi,
                                                   const float* __restrict__ gh,
                                                   const float* __restrict__ states,
                                                   float* __restrict__ out) {
  int b = blockIdx.y;
  int j = blockIdx.x * 256 + threadIdx.x;
  long o = (long)b * 3072;
  float ir = gi[o + j], hr = gh[o + j];
  float iz = gi[o + 1024 + j], hz = gh[o + 1024 + j];
  float in_ = gi[o + 2048 + j], hn = gh[o + 2048 + j];
  float r = 1.f / (1.f + __expf(-(ir + hr)));
  float z = 1.f / (1.f + __expf(-(iz + hz)));
  float n = fast_tanh(in_ + r * hn);
  out[(long)b * 1024 + j] = (1.f - z) * n + z * states[(long)b * 1024 + j];
}

extern "C" void kernel_launch(void* const* d_in, const int* in_sizes, int n_in,
                              void* d_out, int out_size, void* d_ws, size_t ws_size,
                              hipStream_t stream) {
  const float* inputs  = (const float*)d_in[0];
  const float* states  = (const float*)d_in[1];
  const float* encoded = (const float*)d_in[2];
  const float* W_enc   = (const float*)d_in[3];
  const float* b_enc   = (const float*)d_in[4];
  const float* W_dec   = (const float*)d_in[5];
  const float* b_dec   = (const float*)d_in[6];
  const float* w_out   = (const float*)d_in[7];
  // d_in[8] = b_out: softmax-invariant, unused
  const float* W_ih    = (const float*)d_in[9];
  const float* b_ih    = (const float*)d_in[10];
  const float* W_hh    = (const float*)d_in[11];
  const float* b_hh    = (const float*)d_in[12];
  float* out = (float*)d_out;
  float* ws = (float*)d_ws;

  const long ENC_ELEMS = 64L * 1024 * 1024;   // 64*1024*1024 fp32 elements
  const long ENCB_FLOATS = ENC_ELEMS / 2;     // bf16 copy, in float slots

  __bf16* encB = (__bf16*)ws;                 // ws_size confirmed ~1GB (R7 fills)
  float* base = ws + ENCB_FLOATS;

  float* addv = base;                 // 32768
  float* psc  = base + 32768;         // 2*65536 = 131072
  float* wts  = base + 163840;        // 65536
  float* attp = base + 229376;        // 64*16*1024 = 1048576
  float* xcat = base + 1277952;       // 98304
  float* gi   = base + 1376256;       // 196608
  float* gh   = base + 1572864;       // 196608
  __bf16* Wt  = (__bf16*)(base + 1769472);  // 512*1024 bf16 (262144 float slots)
  // base region total 2031616 floats = 8.1 MB (+128MB encB)

  conv_kernel<<<4096, 256, 0, stream>>>(encoded, encB, ENC_ELEMS / 16);

  wenc_t_kernel<<<dim3(32, 16), 256, 0, stream>>>(W_enc, Wt);

  dim3 gA(64, 2);
  dec_proj_kernel<<<gA, 256, 0, stream>>>(states, W_dec, b_enc, b_dec, addv);

  enc_score_kernel<<<512, 512, 0, stream>>>(encB, Wt, addv, w_out, psc);

  softmax_kernel<<<64, 256, 0, stream>>>(psc, wts);

  dim3 gD(16, 64);
  att_part_bf16_kernel<<<gD, 128, 0, stream>>>(encB, wts, attp);

  dim3 gE(6, 64);
  xcat_kernel<<<gE, 256, 0, stream>>>(inputs, attp, xcat);

  gru_gemv_kernel<<<192, 512, 0, stream>>>(xcat, states, W_ih, b_ih, W_hh, b_hh, gi, gh);

  dim3 gG(4, 64);
  gate_kernel<<<gG, 256, 0, stream>>>(gi, gh, states, out);
}

// Round 9
// 337.195 us; speedup vs baseline: 1.0357x; 1.0126x over previous
//
#include <hip/hip_runtime.h>
#include <hip/hip_bf16.h>

// Problem: B=64, S=1024, H=1024, A=512, E=512
// scores = tanh(encoded@W_enc + b_enc + states@W_dec + b_dec) . w_out (+b_out: softmax-invariant)
// weights = softmax(scores); attention = weights . encoded
// GRU: x=[inputs,attention]; gi=x@W_ih+b_ih; gh=states@W_hh+b_hh; gates -> h_new

typedef __attribute__((ext_vector_type(8))) __bf16 bf16x8;
typedef __attribute__((ext_vector_type(4))) __bf16 bf16x4;
typedef __attribute__((ext_vector_type(4))) float f32x4;

__device__ __forceinline__ float fast_tanh(float x) {
  float xa = fminf(fmaxf(x, -15.f), 15.f);
  float e = __expf(2.f * xa);
  return (e - 1.f) / (e + 1.f);
}

// global -> LDS direct DMA, 16B per lane. LDS dest = wave-uniform base + lane*16.
#define GLOAD16(G, L)                                                              \
  __builtin_amdgcn_global_load_lds(                                                \
      (const __attribute__((address_space(1))) unsigned int*)(const void*)(G),     \
      (__attribute__((address_space(3))) unsigned int*)(void*)(L), 16, 0, 0)

// ---------------- Kernel P: convert encoded f32 -> bf16 (streaming)
__global__ __launch_bounds__(256) void conv_kernel(const float* __restrict__ in,
                                                   __bf16* __restrict__ out, long n16) {
  long stride = (long)gridDim.x * 256;
  for (long i = (long)blockIdx.x * 256 + threadIdx.x; i < n16; i += stride) {
    const f32x4* p = (const f32x4*)(in + i * 16);
    f32x4 v0 = p[0], v1 = p[1], v2 = p[2], v3 = p[3];
    bf16x8 o0, o1;
#pragma unroll
    for (int j = 0; j < 4; ++j) {
      o0[j] = (__bf16)v0[j]; o0[4 + j] = (__bf16)v1[j];
      o1[j] = (__bf16)v2[j]; o1[4 + j] = (__bf16)v3[j];
    }
    *(bf16x8*)(out + i * 16) = o0;
    *(bf16x8*)(out + i * 16 + 8) = o1;
  }
}

// ---------------- Kernel T: transpose+convert W_enc [1024][512] f32 -> Wt [512][1024] bf16
__global__ __launch_bounds__(256) void wenc_t_kernel(const float* __restrict__ W,
                                                     __bf16* __restrict__ Wt) {
  __shared__ float tile[32][33];
  int k0 = blockIdx.x * 32, a0 = blockIdx.y * 32;
  int tid = threadIdx.x;
  int r = tid >> 3, c4 = (tid & 7) * 4;
  f32x4 v = *(const f32x4*)(W + (long)(k0 + r) * 512 + a0 + c4);
  tile[r][c4 + 0] = v.x; tile[r][c4 + 1] = v.y;
  tile[r][c4 + 2] = v.z; tile[r][c4 + 3] = v.w;
  __syncthreads();
  int a = tid >> 3, k4 = (tid & 7) * 4;
  bf16x4 o = { (__bf16)tile[k4 + 0][a], (__bf16)tile[k4 + 1][a],
               (__bf16)tile[k4 + 2][a], (__bf16)tile[k4 + 3][a] };
  *(bf16x4*)(Wt + (long)(a0 + a) * 1024 + k0 + k4) = o;
}

// ---------------- Kernel A: addv[b][a] = b_enc[a]+b_dec[a]+sum_h states[b,h]*W_dec[h,a]
__global__ __launch_bounds__(256) void dec_proj_kernel(
    const float* __restrict__ states, const float* __restrict__ W_dec,
    const float* __restrict__ b_enc, const float* __restrict__ b_dec,
    float* __restrict__ addv) {
  int b = blockIdx.x, tid = threadIdx.x;
  int a = blockIdx.y * 256 + tid;
  __shared__ float sl[1024];
  for (int i = tid; i < 1024; i += 256) sl[i] = states[b * 1024 + i];
  __syncthreads();
  float c0 = 0.f, c1 = 0.f, c2 = 0.f, c3 = 0.f;
#pragma unroll 4
  for (int i = 0; i < 256; ++i) {
    c0 += sl[i]         * W_dec[(i)        * 512 + a];
    c1 += sl[i + 256]   * W_dec[(i + 256)  * 512 + a];
    c2 += sl[i + 512]   * W_dec[(i + 512)  * 512 + a];
    c3 += sl[i + 768]   * W_dec[(i + 768)  * 512 + a];
  }
  addv[b * 512 + a] = c0 + c1 + c2 + c3 + b_enc[a] + b_dec[a];
}

// ---------------- Kernel B: 256x256 tile, BK=32, 512 thr / 8 waves (wave = 128x64).
// QUAD-buffered LDS (depth-3 prefetch, 12 loads in flight), ONE barrier per K-step,
// STAGE issued immediately after the barrier (issue-early), counted vmcnt(8) steady —
// never drained in the loop. Safety: per-wave vmcnt precedes s_barrier, so after the
// barrier every wave's tile-kt loads are complete; buf (kt+3)%4's last readers finished
// in iter kt-1, which the barrier also orders. gload_lds with involution source swizzle
// q^((row>>1)&3) (verified R7/R8, conflict-free reads).
// LDS: buf i @ i*32768 (A 16KB + B 16KB), red @ 131072. 135168 B total.
__global__ __launch_bounds__(512, 2) void enc_score_kernel(
    const __bf16* __restrict__ encB,  // [65536][1024] bf16
    const __bf16* __restrict__ Wt,    // [512][1024] bf16 (W_enc^T)
    const float* __restrict__ addv,   // [64][512]
    const float* __restrict__ w_out,  // [512]
    float* __restrict__ psc)          // [2][65536]
{
  __shared__ __attribute__((aligned(16))) char smem[135168];
  float* red = (float*)(smem + 131072);  // [256][4]

  const int d = blockIdx.x;   // 512
  const int xcd = d & 7;
  const int slot = d >> 3;    // 0..63
  const int bn = slot & 1;
  const int bm = ((slot >> 1) << 3) | xcd;  // 0..255; bn-siblings share bm AND xcd

  const int tid = threadIdx.x;
  const int lane = tid & 63;
  const int wid = tid >> 6;   // 0..7
  const int wr = wid >> 2;    // 0..1 (128 rows)
  const int wc = wid & 3;     // 0..3 (64 cols)
  const int lr = lane & 15;
  const int lkb = lane >> 4;  // 0..3

  const long row0 = (long)bm * 256;
  const int col0 = bn * 256;

  // staging: granule (row, q), row = tid>>2 (+128 for 2nd instr), q = tid&3
  // source chunk = q ^ ((row>>1)&3)  (involution; +128 preserves bits 1-2)
  const int sk8 = (tid & 3) ^ ((tid >> 3) & 3);
  const __bf16* gA = encB + (row0 + (tid >> 2)) * 1024 + sk8 * 8;
  const __bf16* gB = Wt + (long)(col0 + (tid >> 2)) * 1024 + sk8 * 8;
  const int ldsW = wid * 1024;  // + lane*16 added by HW

  // fragment read: global chunk lkb lives in LDS slot lkb ^ ((row>>1)&3)
  const int foff = (lkb ^ ((lr >> 1) & 3)) << 4;
  const int aRowB = (wr * 128 + lr) * 64;  // + m*1024 (16 rows)
  const int bColB = (wc * 64 + lr) * 64;   // + n*1024

  f32x4 acc[8][4];
#pragma unroll
  for (int m = 0; m < 8; ++m)
#pragma unroll
    for (int n = 0; n < 4; ++n) acc[m][n] = (f32x4){0.f, 0.f, 0.f, 0.f};

#define STAGE(SBUF, KT) do {                                                       \
    const __bf16* _a = gA + (KT) * 32;                                             \
    const __bf16* _b = gB + (KT) * 32;                                             \
    char* _base = smem + (SBUF) * 32768;                                           \
    GLOAD16(_a,          _base + ldsW);                                            \
    GLOAD16(_a + 131072, _base + 8192 + ldsW);                                     \
    GLOAD16(_b,          _base + 16384 + ldsW);                                    \
    GLOAD16(_b + 131072, _base + 24576 + ldsW);                                    \
  } while (0)

#define COMPUTE(COFF) do {                                                         \
    const char* _Ab = smem + (COFF);                                               \
    const char* _Bb = _Ab + 16384;                                                 \
    bf16x8 _af[8], _bv[4];                                                         \
    _Pragma("unroll") for (int _m = 0; _m < 8; ++_m)                               \
      _af[_m] = *(const bf16x8*)(_Ab + aRowB + _m * 1024 + foff);                  \
    _Pragma("unroll") for (int _n = 0; _n < 4; ++_n)                               \
      _bv[_n] = *(const bf16x8*)(_Bb + bColB + _n * 1024 + foff);                  \
    __builtin_amdgcn_s_setprio(1);                                                 \
    _Pragma("unroll") for (int _m = 0; _m < 8; ++_m)                               \
      _Pragma("unroll") for (int _n = 0; _n < 4; ++_n)                             \
        acc[_m][_n] =                                                              \
            __builtin_amdgcn_mfma_f32_16x16x32_bf16(_af[_m], _bv[_n], acc[_m][_n], 0, 0, 0); \
    __builtin_amdgcn_s_setprio(0);                                                 \
  } while (0)

#define WAITBAR(N) do {                                                            \
    asm volatile("s_waitcnt vmcnt(" #N ")" ::: "memory");                          \
    __builtin_amdgcn_sched_barrier(0);                                             \
    __builtin_amdgcn_s_barrier();                                                  \
    __builtin_amdgcn_sched_barrier(0);                                             \
  } while (0)

  // prologue: tiles 0,1,2 in flight (12 outstanding loads/thread)
  STAGE(0, 0);
  STAGE(1, 1);
  STAGE(2, 2);

  for (int kt = 0; kt < 29; ++kt) {
    WAITBAR(8);                       // tile kt complete (all waves, via barrier)
    STAGE((kt + 3) & 3, kt + 3);      // issue-early; buf freed in iter kt-1
    __builtin_amdgcn_sched_barrier(0);
    COMPUTE((kt & 3) * 32768);
  }
  WAITBAR(8);
  COMPUTE(1 * 32768);                 // kt=29
  WAITBAR(4);
  COMPUTE(2 * 32768);                 // kt=30
  WAITBAR(0);
  COMPUTE(3 * 32768);                 // kt=31

#undef STAGE
#undef COMPUTE
#undef WAITBAR

  // Epilogue: per-row sum of tanh(acc + addv[b][col]) * w_out[col]
  // C/D layout: col = lane&15, row = (lane>>4)*4 + reg
  const int b = bm >> 2;  // 256 rows/block, 1024/batch
  const float* addvb = addv + b * 512;
  float rowsum[8][4];
#pragma unroll
  for (int m = 0; m < 8; ++m)
#pragma unroll
    for (int reg = 0; reg < 4; ++reg) rowsum[m][reg] = 0.f;

#pragma unroll
  for (int m = 0; m < 8; ++m) {
#pragma unroll
    for (int n = 0; n < 4; ++n) {
      int col = col0 + wc * 64 + n * 16 + lr;
      float av = addvb[col];
      float wo = w_out[col];
#pragma unroll
      for (int reg = 0; reg < 4; ++reg)
        rowsum[m][reg] += fast_tanh(acc[m][n][reg] + av) * wo;
    }
  }
#pragma unroll
  for (int m = 0; m < 8; ++m)
#pragma unroll
    for (int reg = 0; reg < 4; ++reg) {
      float v = rowsum[m][reg];
      v += __shfl_xor(v, 1, 64);
      v += __shfl_xor(v, 2, 64);
      v += __shfl_xor(v, 4, 64);
      v += __shfl_xor(v, 8, 64);
      rowsum[m][reg] = v;
    }
  __syncthreads();
  if (lr == 0) {
#pragma unroll
    for (int m = 0; m < 8; ++m)
#pragma unroll
      for (int reg = 0; reg < 4; ++reg)
        red[(wr * 128 + m * 16 + lkb * 4 + reg) * 4 + wc] = rowsum[m][reg];
  }
  __syncthreads();
  if (tid < 256)
    psc[(long)bn * 65536 + row0 + tid] =
        red[tid * 4] + red[tid * 4 + 1] + red[tid * 4 + 2] + red[tid * 4 + 3];
}

// ---------------- Kernel C: softmax over S=1024 per batch (2 psc partials)
__global__ __launch_bounds__(256) void softmax_kernel(const float* __restrict__ psc,
                                                      float* __restrict__ wts) {
  int b = blockIdx.x, tid = threadIdx.x;
  __shared__ float sred[8];
  float sc[4];
  float mx = -1e30f;
#pragma unroll
  for (int i = 0; i < 4; ++i) {
    long r = (long)b * 1024 + tid + i * 256;
    sc[i] = psc[r] + psc[65536 + r];
    mx = fmaxf(mx, sc[i]);
  }
  for (int off = 1; off < 64; off <<= 1) mx = fmaxf(mx, __shfl_xor(mx, off, 64));
  if ((tid & 63) == 0) sred[tid >> 6] = mx;
  __syncthreads();
  mx = fmaxf(fmaxf(sred[0], sred[1]), fmaxf(sred[2], sred[3]));
  float e[4], sum = 0.f;
#pragma unroll
  for (int i = 0; i < 4; ++i) {
    e[i] = __expf(sc[i] - mx);
    sum += e[i];
  }
  for (int off = 1; off < 64; off <<= 1) sum += __shfl_xor(sum, off, 64);
  if ((tid & 63) == 0) sred[4 + (tid >> 6)] = sum;
  __syncthreads();
  sum = sred[4] + sred[5] + sred[6] + sred[7];
  float inv = 1.f / sum;
#pragma unroll
  for (int i = 0; i < 4; ++i) wts[(long)b * 1024 + tid + i * 256] = e[i] * inv;
}

// ---------------- Kernel D: attention partials from bf16 encB (16 chunks of 64 s)
__global__ __launch_bounds__(128) void att_part_bf16_kernel(const __bf16* __restrict__ encB,
                                                            const float* __restrict__ wts,
                                                            float* __restrict__ attp) {
  int chunk = blockIdx.x;  // 16
  int b = blockIdx.y;      // 64
  int tid = threadIdx.x;   // 0..127 -> h octet
  const __bf16* base = encB + ((long)b * 1024 + chunk * 64) * 1024 + tid * 8;
  const float* w = wts + b * 1024 + chunk * 64;
  float a0[8], a1[8];
#pragma unroll
  for (int j = 0; j < 8; ++j) { a0[j] = 0.f; a1[j] = 0.f; }
#pragma unroll 4
  for (int s = 0; s < 64; s += 2) {
    bf16x8 v0 = *(const bf16x8*)(base + (long)s * 1024);
    bf16x8 v1 = *(const bf16x8*)(base + (long)(s + 1) * 1024);
    float w0 = w[s], w1 = w[s + 1];
#pragma unroll
    for (int j = 0; j < 8; ++j) {
      a0[j] += (float)v0[j] * w0;
      a1[j] += (float)v1[j] * w1;
    }
  }
  float* o = attp + ((long)(b * 16 + chunk)) * 1024 + tid * 8;
#pragma unroll
  for (int j = 0; j < 8; ++j) o[j] = a0[j] + a1[j];
}

// ---------------- Kernel E: xcat[b][0:512]=inputs, xcat[b][512:1536]=sum_chunk attp
__global__ __launch_bounds__(256) void xcat_kernel(const float* __restrict__ inputs,
                                                   const float* __restrict__ attp,
                                                   float* __restrict__ xcat) {
  int b = blockIdx.y;
  int k = blockIdx.x * 256 + threadIdx.x;  // 0..1535
  float v;
  if (k < 512) {
    v = inputs[b * 512 + k];
  } else {
    int h = k - 512;
    v = 0.f;
#pragma unroll
    for (int c = 0; c < 16; ++c) v += attp[((long)(b * 16 + c)) * 1024 + h];
  }
  xcat[(long)b * 1536 + k] = v;
}

// ---------------- Kernel F: GRU GEMVs, batch-grouped: chunk-group pinned to one XCD
__global__ __launch_bounds__(512) void gru_gemv_kernel(
    const float* __restrict__ xcat, const float* __restrict__ states,
    const float* __restrict__ W_ih, const float* __restrict__ b_ih,
    const float* __restrict__ W_hh, const float* __restrict__ b_hh,
    float* __restrict__ gi, float* __restrict__ gh) {
  __shared__ float sx[12288];
  const int dd = blockIdx.x;            // 192
  const int xcd = dd & 7;
  const int n = dd >> 3;
  const int cgrp = xcd + 8 * (n >> 3);
  const int bg = n & 7;
  const int tid = threadIdx.x;
  const int lcol = tid & 255;
  const int bsel = (tid >> 8) * 4;

  if (cgrp < 12) {
    const int col = cgrp * 256 + lcol;
    const float* xb = xcat + (long)bg * 8 * 1536;
    for (int i = tid; i < 3072; i += 512) ((f32x4*)sx)[i] = ((const f32x4*)xb)[i];
    __syncthreads();
    float a0 = b_ih[col], a1 = a0, a2 = a0, a3 = a0;
    const float* x0 = sx + (bsel + 0) * 1536;
    const float* x1 = sx + (bsel + 1) * 1536;
    const float* x2 = sx + (bsel + 2) * 1536;
    const float* x3 = sx + (bsel + 3) * 1536;
    for (int k = 0; k < 1536; k += 4) {
      f32x4 v0 = *(const f32x4*)(x0 + k);
      f32x4 v1 = *(const f32x4*)(x1 + k);
      f32x4 v2 = *(const f32x4*)(x2 + k);
      f32x4 v3 = *(const f32x4*)(x3 + k);
#pragma unroll
      for (int j = 0; j < 4; ++j) {
        float w = W_ih[(long)(k + j) * 3072 + col];
        a0 += v0[j] * w; a1 += v1[j] * w; a2 += v2[j] * w; a3 += v3[j] * w;
      }
    }
    long o = (long)(bg * 8 + bsel) * 3072 + col;
    gi[o] = a0; gi[o + 3072] = a1; gi[o + 6144] = a2; gi[o + 9216] = a3;
  } else {
    const int col = (cgrp - 12) * 256 + lcol;
    const float* sb = states + (long)bg * 8 * 1024;
    for (int i = tid; i < 2048; i += 512) ((f32x4*)sx)[i] = ((const f32x4*)sb)[i];
    __syncthreads();
    float a0 = b_hh[col], a1 = a0, a2 = a0, a3 = a0;
    const float* x0 = sx + (bsel + 0) * 1024;
    const float* x1 = sx + (bsel + 1) * 1024;
    const float* x2 = sx + (bsel + 2) * 1024;
    const float* x3 = sx + (bsel + 3) * 1024;
    for (int k = 0; k < 1024; k += 4) {
      f32x4 v0 = *(const f32x4*)(x0 + k);
      f32x4 v1 = *(const f32x4*)(x1 + k);
      f32x4 v2 = *(const f32x4*)(x2 + k);
      f32x4 v3 = *(const f32x4*)(x3 + k);
#pragma unroll
      for (int j = 0; j < 4; ++j) {
        float w = W_hh[(long)(k + j) * 3072 + col];
        a0 += v0[j] * w; a1 += v1[j] * w; a2 += v2[j] * w; a3 += v3[j] * w;
      }
    }
    long o = (long)(bg * 8 + bsel) * 3072 + col;
    gh[o] = a0; gh[o + 3072] = a1; gh[o + 6144] = a2; gh[o + 9216] = a3;
  }
}

// ---------------- Kernel G: gates
__global__ __launch_bounds__(256) void gate_kernel(const float* __restrict__ gi,
                                                   const float* __restrict__ gh,
                                                   const float* __restrict__ states,
                                                   float* __restrict__ out) {
  int b = blockIdx.y;
  int j = blockIdx.x * 256 + threadIdx.x;
  long o = (long)b * 3072;
  float ir = gi[o + j], hr = gh[o + j];
  float iz = gi[o + 1024 + j], hz = gh[o + 1024 + j];
  float in_ = gi[o + 2048 + j], hn = gh[o + 2048 + j];
  float r = 1.f / (1.f + __expf(-(ir + hr)));
  float z = 1.f / (1.f + __expf(-(iz + hz)));
  float n = fast_tanh(in_ + r * hn);
  out[(long)b * 1024 + j] = (1.f - z) * n + z * states[(long)b * 1024 + j];
}

extern "C" void kernel_launch(void* const* d_in, const int* in_sizes, int n_in,
                              void* d_out, int out_size, void* d_ws, size_t ws_size,
                              hipStream_t stream) {
  const float* inputs  = (const float*)d_in[0];
  const float* states  = (const float*)d_in[1];
  const float* encoded = (const float*)d_in[2];
  const float* W_enc   = (const float*)d_in[3];
  const float* b_enc   = (const float*)d_in[4];
  const float* W_dec   = (const float*)d_in[5];
  const float* b_dec   = (const float*)d_in[6];
  const float* w_out   = (const float*)d_in[7];
  // d_in[8] = b_out: softmax-invariant, unused
  const float* W_ih    = (const float*)d_in[9];
  const float* b_ih    = (const float*)d_in[10];
  const float* W_hh    = (const float*)d_in[11];
  const float* b_hh    = (const float*)d_in[12];
  float* out = (float*)d_out;
  float* ws = (float*)d_ws;

  const long ENC_ELEMS = 64L * 1024 * 1024;   // encoded fp32 elements
  const long ENCB_FLOATS = ENC_ELEMS / 2;     // bf16 copy, in float slots

  __bf16* encB = (__bf16*)ws;
  float* base = ws + ENCB_FLOATS;

  float* addv = base;                 // 32768
  float* psc  = base + 32768;         // 2*65536 = 131072
  float* wts  = base + 163840;        // 65536
  float* attp = base + 229376;        // 64*16*1024 = 1048576
  float* xcat = base + 1277952;       // 98304
  float* gi   = base + 1376256;       // 196608
  float* gh   = base + 1572864;       // 196608
  __bf16* Wt  = (__bf16*)(base + 1769472);  // 512*1024 bf16

  conv_kernel<<<4096, 256, 0, stream>>>(encoded, encB, ENC_ELEMS / 16);

  wenc_t_kernel<<<dim3(32, 16), 256, 0, stream>>>(W_enc, Wt);

  dim3 gA(64, 2);
  dec_proj_kernel<<<gA, 256, 0, stream>>>(states, W_dec, b_enc, b_dec, addv);

  enc_score_kernel<<<512, 512, 0, stream>>>(encB, Wt, addv, w_out, psc);

  softmax_kernel<<<64, 256, 0, stream>>>(psc, wts);

  dim3 gD(16, 64);
  att_part_bf16_kernel<<<gD, 128, 0, stream>>>(encB, wts, attp);

  dim3 gE(6, 64);
  xcat_kernel<<<gE, 256, 0, stream>>>(inputs, attp, xcat);

  gru_gemv_kernel<<<192, 512, 0, stream>>>(xcat, states, W_ih, b_ih, W_hh, b_hh, gi, gh);

  dim3 gG(4, 64);
  gate_kernel<<<gG, 256, 0, stream>>>(gi, gh, states, out);
}